// Round 14
// baseline (106.253 us; speedup 1.0000x reference)
//
#include <hip/hip_runtime.h>
#include <math.h>

#define NQ   10
#define DIM  1024
#define NB   10
#define NPTS 128
#define S2   0.70710678118654752440f

#define TS 32
#define KC 64
#define KSPLIT (DIM / KC)       // 16
#define NBLK_RED 64             // reduce_final grid

typedef float f2 __attribute__((ext_vector_type(2)));   // (re, im)

__device__ __forceinline__ f2 cmul(f2 a, f2 b) {
    return (f2){a.x * b.x - a.y * b.y, a.x * b.y + a.y * b.x};
}

// ---------------------------------------------------------------------------
// Kernel A: psi(x) = F(x, params)|0>. ONE WAVE (64 threads) per point.
// 16 amps/thread; three layouts so ALL butterfly levels are register-local
// (zero shuffles, zero barriers; LDS ops are wave-synchronous — proven r9):
//   L1: d = (lane<<4)|m      regs = d[3:0]  -> qubits 6,7,8,9
//   L2: d = (u<<8)|(m<<4)|l4 regs = d[7:4]  -> qubits 2,3,4,5  (lane=(u<<4)|l4)
//   L3: d = (m<<6)|lane      regs = d[9:6]  -> qubits 0,1,2,3
// Even blocks: L1 -apply{6..9}-> T -> L2 -apply{2..5}-> T -> L3 -apply{0,1}-CRZ
// Odd  blocks: L3 -apply{0..3}-> T -> L2 -apply{4,5}->  T -> L1 -apply{6..9}-CRZ
// Per-block U_q = RY(th)RZ(x)H fused 2x2 (proven r11/r12, absmax 0.0).
// CRZ diagonal via parity-matched cis tables (no in-loop sincos).
// Block 0 collapsed to a product state directly in L3.
// Transpose buffer T[m][lane], pitch 65 f2: writes conflict-free (contiguous
// per instruction), reads 4-way (1.58x, cheap). #pragma unroll 1 keeps the
// body ~27 KB (inside 32 KB I-cache; the r12 full unroll was ~43 KB).
// ---------------------------------------------------------------------------
__global__ __launch_bounds__(64)
void states_kernel(const float* __restrict__ data,
                   const float* __restrict__ params,
                   float2* __restrict__ psi,
                   double* __restrict__ acc,
                   int* __restrict__ cnt)
{
    __shared__ f2    T[16 * 65];       // transpose buffer (pitch 65 f2)
    __shared__ f2    UT[NB * NQ * 4];  // fused 2x2 U per (block, qubit)
    __shared__ f2    Lt[NB * 64];      // CRZ cis(lane part), parity-matched
    __shared__ f2    Gt[NB * 64];      // CRZ cis(reg+cross part), parity-matched
    __shared__ float sCrz[NB * NQ];    // CRZ angles

    const int lane = threadIdx.x;      // 0..63, one wave
    const int pt   = blockIdx.x;

    if (pt == 0 && lane == 0) { acc[0] = 0.0; acc[1] = 0.0; cnt[0] = 0; }

    // ---------------- staging 1: U matrices + CRZ angles ----------------
    for (int e = lane; e < NB * NQ; e += 64) {
        const int j = e / NQ, q = e - j * NQ;
        float c, s;
        __sincosf(0.5f * params[j * 2 * NQ + q], &s, &c);
        float cx, sx;
        __sincosf(0.5f * data[pt * (NB * NQ) + e], &sx, &cx);
        const float al = (c - s) * S2, be = (c + s) * S2;
        f2* u = &UT[e * 4];
        u[0] = (f2){ al * cx, -be * sx};
        u[1] = (f2){ be * cx, -al * sx};
        u[2] = (f2){ be * cx,  al * sx};
        u[3] = (f2){-al * cx, -be * sx};
        sCrz[e] = params[j * 2 * NQ + NQ + q];
    }
    // ---------------- staging 2: CRZ cis tables (wave-synchronous) -------
    for (int e = lane; e < NB * 64; e += 64) {     // 10 iterations
        const int j = e >> 6, r = e & 63;
        const float* phi = &sCrz[j * NQ];
        const float r0 = (float)(r & 1),        r1 = (float)((r >> 1) & 1);
        const float r2 = (float)((r >> 2) & 1), r3 = (float)((r >> 3) & 1);
        const float r4 = (float)((r >> 4) & 1), r5 = (float)((r >> 5) & 1);
        // Gt index: r = (m<<2)|(bA<<1)|bB
        const float m0 = r2, m1 = r3, m2 = r4, m3 = r5;
        const float bA = r1, bB = r0;
        float L, G;
        if ((j & 1) == 0) {   // even -> layout L3 (lane = d[5:0])
            L = phi[4] * r5 * (r4 - 0.5f) + phi[5] * r4 * (r3 - 0.5f)
              + phi[6] * r3 * (r2 - 0.5f) + phi[7] * r2 * (r1 - 0.5f)
              + phi[8] * r1 * (r0 - 0.5f);
            G = phi[0] * m3 * (m2 - 0.5f) + phi[1] * m2 * (m1 - 0.5f)
              + phi[2] * m1 * (m0 - 0.5f) + phi[3] * m0 * (bA - 0.5f)
              + phi[9] * bB * (m3 - 0.5f);
        } else {              // odd -> layout L1 (lane = d[9:4])
            L = phi[0] * r5 * (r4 - 0.5f) + phi[1] * r4 * (r3 - 0.5f)
              + phi[2] * r3 * (r2 - 0.5f) + phi[3] * r2 * (r1 - 0.5f)
              + phi[4] * r1 * (r0 - 0.5f);
            G = phi[6] * m3 * (m2 - 0.5f) + phi[7] * m2 * (m1 - 0.5f)
              + phi[8] * m1 * (m0 - 0.5f) + phi[5] * bA * (m3 - 0.5f)
              + phi[9] * m0 * (bB - 0.5f);
        }
        float s, c;
        __sincosf(L, &s, &c);  Lt[e] = (f2){c, s};
        __sincosf(G, &s, &c);  Gt[e] = (f2){c, s};
    }

    #define APPLY(j, q, bit) { \
        const f2* _u = &UT[((j) * NQ + (q)) * 4]; \
        const f2 u0 = _u[0], u1 = _u[1], u2 = _u[2], u3 = _u[3]; \
        _Pragma("unroll") \
        for (int m = 0; m < 16; ++m) if (!(m & (bit))) { \
            const f2 a0 = v[m], a1 = v[m | (bit)]; \
            v[m]         = cmul(u0, a0) + cmul(u1, a1); \
            v[m | (bit)] = cmul(u2, a0) + cmul(u3, a1); \
        } }

    #define TWRITE() { \
        _Pragma("unroll") \
        for (int m = 0; m < 16; ++m) T[m * 65 + lane] = v[m]; }

    // L1-stored -> L2 regs, and L2-stored -> L1 regs (same formula)
    #define READ_AD() { \
        const int base = 65 * (lane & 15) + ((lane >> 4) << 4); \
        _Pragma("unroll") \
        for (int m = 0; m < 16; ++m) v[m] = T[base + m]; }

    // L2-stored -> L3 regs
    #define READ_B() { \
        _Pragma("unroll") \
        for (int m = 0; m < 16; ++m) \
            v[m] = T[65 * (((m & 3) << 2) | (lane >> 4)) + ((m >> 2) << 4) + (lane & 15)]; }

    // L3-stored -> L2 regs
    #define READ_C() { \
        _Pragma("unroll") \
        for (int m = 0; m < 16; ++m) \
            v[m] = T[65 * (((lane >> 4) << 2) | (m >> 2)) + ((m & 3) << 4) + (lane & 15)]; }

    #define CRZ(j, crossIdx) { \
        const f2 l = Lt[((j) << 6) | lane]; \
        _Pragma("unroll") \
        for (int m = 0; m < 16; ++m) { \
            const f2 g = Gt[((j) << 6) | (m << 2) | (crossIdx)]; \
            v[m] = cmul(v[m], cmul(l, g)); \
        } }

    // ---- block 0 collapsed: |0> -> product state directly in L3 ----
    f2 v[16];
    {
        // lane factor: qubits 4..9 <-> lane bits 5..0 (q = 9-k)
        f2 f = cmul(UT[9 * 4 + (lane & 1) * 2],        UT[8 * 4 + ((lane >> 1) & 1) * 2]);
        f = cmul(f, cmul(UT[7 * 4 + ((lane >> 2) & 1) * 2], UT[6 * 4 + ((lane >> 3) & 1) * 2]));
        f = cmul(f, cmul(UT[5 * 4 + ((lane >> 4) & 1) * 2], UT[4 * 4 + ((lane >> 5) & 1) * 2]));
        #pragma unroll
        for (int m = 0; m < 16; ++m) {
            const f2 rm = cmul(cmul(UT[0 * 4 + ((m >> 3) & 1) * 2],
                                    UT[1 * 4 + ((m >> 2) & 1) * 2]),
                               cmul(UT[2 * 4 + ((m >> 1) & 1) * 2],
                                    UT[3 * 4 + (m & 1) * 2]));
            v[m] = cmul(rm, f);
        }
    }
    const int crossEven = (((lane >> 5) & 1) << 1) | (lane & 1);   // (d5<<1)|d0 in L3
    const int crossOdd  = ((lane & 1) << 1) | ((lane >> 5) & 1);   // (d4<<1)|d9 in L1
    CRZ(0, crossEven)

    // ---- blocks 1..9 (odd starts L3, even starts L1) ----
    #pragma unroll 1
    for (int j = 1; j < NB; ++j) {
        if (j & 1) {          // odd: L3 -> L2 -> L1
            APPLY(j, 0, 8) APPLY(j, 1, 4) APPLY(j, 2, 2) APPLY(j, 3, 1)
            TWRITE() READ_C()
            APPLY(j, 4, 2) APPLY(j, 5, 1)
            TWRITE() READ_AD()
            APPLY(j, 6, 8) APPLY(j, 7, 4) APPLY(j, 8, 2) APPLY(j, 9, 1)
            CRZ(j, crossOdd)
        } else {              // even: L1 -> L2 -> L3
            APPLY(j, 6, 8) APPLY(j, 7, 4) APPLY(j, 8, 2) APPLY(j, 9, 1)
            TWRITE() READ_AD()
            APPLY(j, 2, 8) APPLY(j, 3, 4) APPLY(j, 4, 2) APPLY(j, 5, 1)
            TWRITE() READ_B()
            APPLY(j, 0, 8) APPLY(j, 1, 4)
            CRZ(j, crossEven)
        }
    }

    // ---- write out (block 9 odd ends in L1: d = (lane<<4)|m) ----
    float2* o = psi + (size_t)pt * DIM + lane * 16;
    #pragma unroll
    for (int k = 0; k < 8; ++k)
        *(float4*)&o[2 * k] = make_float4(v[2*k].x, v[2*k].y, v[2*k+1].x, v[2*k+1].y);
}

// ---------------------------------------------------------------------------
// Kernel B: tiled complex Gram (proven rounds 2/5/6/8-12). 32x32 tile x 16
// K-chunks = 256 blocks. Coalesced float4 staging; A broadcast / Bt <=2-way
// LDS reads; 2x2 register accumulator per thread.
// ---------------------------------------------------------------------------
__global__ __launch_bounds__(256)
void gram_kernel(const float2* __restrict__ psi, float2* __restrict__ Gpart)
{
    __shared__ float2 A [TS][KC + 2];   // pitch 66 float2
    __shared__ float2 Bt[KC][TS + 2];   // pitch 34 float2

    const int tid  = threadIdx.x;
    const int bx   = blockIdx.x;
    const int ks   = bx & 15;
    const int tile = bx >> 4;
    const int ti   = tile >> 2, tj = tile & 3;
    const int kbase = ks * KC;

    #pragma unroll
    for (int it = 0; it < 2; ++it) {
        const int slot = it * 256 + tid;
        const int row  = slot >> 4;          // 0..31
        const int kq   = (slot & 15) << 2;   // 0,4,...,60
        const float4* sa = (const float4*)(psi + (ti * TS + row) * DIM + kbase + kq);
        const float4 a01 = sa[0], a23 = sa[1];
        *(float4*)&A[row][kq]     = a01;
        *(float4*)&A[row][kq + 2] = a23;
        const float4* sb = (const float4*)(psi + (tj * TS + row) * DIM + kbase + kq);
        const float4 b01 = sb[0], b23 = sb[1];
        Bt[kq + 0][row] = make_float2(b01.x, b01.y);
        Bt[kq + 1][row] = make_float2(b01.z, b01.w);
        Bt[kq + 2][row] = make_float2(b23.x, b23.y);
        Bt[kq + 3][row] = make_float2(b23.z, b23.w);
    }
    __syncthreads();

    const int ty = tid >> 4, tx = tid & 15;
    float g00r = 0.f, g00i = 0.f, g01r = 0.f, g01i = 0.f;
    float g10r = 0.f, g10i = 0.f, g11r = 0.f, g11i = 0.f;

    #pragma unroll 4
    for (int k = 0; k < KC; k += 2) {
        const float4 a0 = *(const float4*)&A[2 * ty    ][k];
        const float4 a1 = *(const float4*)&A[2 * ty + 1][k];
        const float4 b0 = *(const float4*)&Bt[k    ][2 * tx];
        const float4 b1 = *(const float4*)&Bt[k + 1][2 * tx];
        g00r += a0.x * b0.x + a0.y * b0.y;  g00i += a0.x * b0.y - a0.y * b0.x;
        g01r += a0.x * b0.z + a0.y * b0.w;  g01i += a0.x * b0.w - a0.y * b0.z;
        g10r += a1.x * b0.x + a1.y * b0.y;  g10i += a1.x * b0.y - a1.y * b0.x;
        g11r += a1.x * b0.z + a1.y * b0.w;  g11i += a1.x * b0.w - a1.y * b0.z;
        g00r += a0.z * b1.x + a0.w * b1.y;  g00i += a0.z * b1.y - a0.w * b1.x;
        g01r += a0.z * b1.z + a0.w * b1.w;  g01i += a0.z * b1.w - a0.w * b1.z;
        g10r += a1.z * b1.x + a1.w * b1.y;  g10i += a1.z * b1.y - a1.w * b1.x;
        g11r += a1.z * b1.z + a1.w * b1.w;  g11i += a1.z * b1.w - a1.w * b1.z;
    }

    float2* gp = Gpart + ks * (NPTS * NPTS);
    const int gr0 = ti * TS + 2 * ty, gc0 = tj * TS + 2 * tx;
    gp[(gr0    ) * NPTS + gc0    ] = make_float2(g00r, g00i);
    gp[(gr0    ) * NPTS + gc0 + 1] = make_float2(g01r, g01i);
    gp[(gr0 + 1) * NPTS + gc0    ] = make_float2(g10r, g10i);
    gp[(gr0 + 1) * NPTS + gc0 + 1] = make_float2(g11r, g11i);
}

// ---------------------------------------------------------------------------
// Kernel C: sum K-partials (coalesced), K = |G|^2, reduce polarity & sum(K^2);
// last-finishing block (atomic counter, proven) writes the scalar.
// ---------------------------------------------------------------------------
__global__ __launch_bounds__(256)
void reduce_final(const float2* __restrict__ Gpart,
                  const float* __restrict__ labels,
                  double* __restrict__ acc,
                  int* __restrict__ cnt,
                  float* __restrict__ out)
{
    const int idx = blockIdx.x * 256 + threadIdx.x;   // 0..16383
    float gr = 0.f, gi = 0.f;
    #pragma unroll
    for (int p = 0; p < KSPLIT; ++p) {
        const float2 g = Gpart[p * (NPTS * NPTS) + idx];
        gr += g.x; gi += g.y;
    }
    const int i  = idx >> 7;
    const int jj = idx & (NPTS - 1);
    const float K = gr * gr + gi * gi;
    double pol = (double)(labels[i] * labels[jj]) * (double)K;
    double k2  = (double)K * (double)K;
    #pragma unroll
    for (int off = 1; off < 64; off <<= 1) {
        pol += __shfl_xor(pol, off, 64);
        k2  += __shfl_xor(k2,  off, 64);
    }
    __shared__ double sp[4], sk[4];
    const int wv = threadIdx.x >> 6;
    if ((threadIdx.x & 63) == 0) { sp[wv] = pol; sk[wv] = k2; }
    __syncthreads();
    if (threadIdx.x == 0) {
        atomicAdd(&acc[0], sp[0] + sp[1] + sp[2] + sp[3]);
        atomicAdd(&acc[1], sk[0] + sk[1] + sk[2] + sk[3]);
        __threadfence();
        const int done = atomicAdd(cnt, 1);
        if (done == NBLK_RED - 1) {
            const double p  = atomicAdd(&acc[0], 0.0);   // atomic read
            const double s2 = atomicAdd(&acc[1], 0.0);
            double sumL2 = 0.0;
            for (int t = 0; t < NPTS; ++t) {
                const double l = (double)labels[t];
                sumL2 += l * l;
            }
            out[0] = (float)(p / (sumL2 * sqrt(s2)));
        }
    }
}

// ---------------------------------------------------------------------------
extern "C" void kernel_launch(void* const* d_in, const int* in_sizes, int n_in,
                              void* d_out, int out_size, void* d_ws, size_t ws_size,
                              hipStream_t stream)
{
    const float* data   = (const float*)d_in[0];   // [128,100]
    const float* labels = (const float*)d_in[1];   // [128]
    const float* params = (const float*)d_in[2];   // [10,2,10]
    float* out = (float*)d_out;

    float2* psi   = (float2*)d_ws;                                   // 1 MiB
    float2* Gpart = (float2*)((char*)d_ws + (size_t)(1u << 20));     // 2 MiB
    double* acc   = (double*)((char*)d_ws + (size_t)(3u << 20));     // 16 B
    int*    cnt   = (int*)   ((char*)d_ws + (size_t)(3u << 20) + 16);

    states_kernel<<<NPTS, 64, 0, stream>>>(data, params, psi, acc, cnt);
    gram_kernel<<<256, 256, 0, stream>>>(psi, Gpart);
    reduce_final<<<NBLK_RED, 64 * 4, 0, stream>>>(Gpart, labels, acc, cnt, out);
}

// Round 15
// 86.939 us; speedup vs baseline: 1.2222x; 1.2222x over previous
//
#include <hip/hip_runtime.h>
#include <math.h>

#define NQ   10
#define DIM  1024
#define NB   10
#define NPTS 128
#define S2   0.70710678118654752440f

#define TS 32
#define KC 64
#define KSPLIT (DIM / KC)       // 16
#define NBLK_RED 64             // reduce_final grid

typedef float f2 __attribute__((ext_vector_type(2)));   // (re, im)

__device__ __forceinline__ f2 cmul(f2 a, f2 b) {
    return (f2){a.x * b.x - a.y * b.y, a.x * b.y + a.y * b.x};
}

// ---------------------------------------------------------------------------
// Kernel A: psi(x) = F(x, params)|0>. 256 threads (4 waves) per point,
// 4 amps/thread, SHUFFLE-FREE (r14-proven technique at 4x thread count):
// layout L_k (k=0..4): amp d = (t & (4^k-1)) | (m << 2k) | ((t >> 2k) << (2k+2))
//   -> reg bits m = d[2k+1:2k]. Per circuit block: sweep L0->L4 (even j) or
// L4->L0 (odd j): at layout k apply qubits q=9-2k (m bit0) and q=8-2k (m bit1)
// register-locally; 4 padded ping-pong LDS transposes (1 barrier each) move
// between layouts. U_q = RY(th)RZ(x)H fused 2x2 (proven r11/r12/r14).
// CRZ diagonal via parity-matched cis tables (Lt: thread part, Gt: reg+cross
// part) - zero in-loop sincos. Block 0 collapsed to a product state in L4.
// #pragma unroll 1 keeps the body inside I-cache. 20 transpose indices
// precomputed in VGPRs.
// ---------------------------------------------------------------------------
__global__ __launch_bounds__(256)
void states_kernel(const float* __restrict__ data,
                   const float* __restrict__ params,
                   float2* __restrict__ psi,
                   double* __restrict__ acc,
                   int* __restrict__ cnt)
{
    __shared__ f2    Tb[2][1088];      // padded transpose buffers (idx + idx>>4)
    __shared__ f2    UT[NB * NQ * 4];  // fused 2x2 U per (block, qubit)
    __shared__ f2    Lt[NB * 256];     // CRZ cis(thread part), parity-matched
    __shared__ f2    Gt[NB * 16];      // CRZ cis(reg+cross part), parity-matched
    __shared__ float sCrz[NB * NQ];    // CRZ angles

    const int t  = threadIdx.x;        // 0..255
    const int pt = blockIdx.x;

    if (pt == 0 && t == 0) { acc[0] = 0.0; acc[1] = 0.0; cnt[0] = 0; }

    // ---------------- staging 1: U matrices + CRZ angles ----------------
    if (t < NB * NQ) {
        const int j = t / NQ, q = t - j * NQ;
        float c, s;
        __sincosf(0.5f * params[j * 2 * NQ + q], &s, &c);
        float cx, sx;
        __sincosf(0.5f * data[pt * (NB * NQ) + t], &sx, &cx);
        const float al = (c - s) * S2, be = (c + s) * S2;
        f2* u = &UT[t * 4];
        u[0] = (f2){ al * cx, -be * sx};
        u[1] = (f2){ be * cx, -al * sx};
        u[2] = (f2){ be * cx,  al * sx};
        u[3] = (f2){-al * cx, -be * sx};
        sCrz[t] = params[j * 2 * NQ + NQ + q];
    }
    __syncthreads();

    // ---------------- staging 2: CRZ cis tables ----------------
    // Gt: 10 x 16, index (m<<2)|(bA<<1)|bB where bA = t bit7, bB = t bit0.
    if (t < NB * 16) {
        const int j = t >> 4, r = t & 15;
        const float m1 = (float)((r >> 3) & 1), m0 = (float)((r >> 2) & 1);
        const float bA = (float)((r >> 1) & 1), bB = (float)(r & 1);
        const float* phi = &sCrz[j * NQ];
        float G;
        if ((j & 1) == 0)   // even -> ends L4: m=(s0,s1), cross s2=t7, s9=t0
            G = phi[0] * m1 * (m0 - 0.5f) + phi[1] * m0 * (bA - 0.5f)
              + phi[9] * bB * (m1 - 0.5f);
        else                // odd -> ends L0: m=(s8,s9), cross s7=t0, s0=t7
            G = phi[7] * bB * (m1 - 0.5f) + phi[8] * m1 * (m0 - 0.5f)
              + phi[9] * m0 * (bA - 0.5f);
        float s, c;
        __sincosf(G, &s, &c);
        Gt[t] = (f2){c, s};
    }
    // Lt: 10 x 256 thread-part phases (7 terms each), parity-matched.
    #pragma unroll 1
    for (int j = 0; j < NB; ++j) {
        const float* phi = &sCrz[j * NQ];
        float L = 0.f;
        if ((j & 1) == 0) {   // even (L4): s_q = t>>(9-q), q=2..9; terms q=2..8
            #pragma unroll
            for (int q = 2; q <= 8; ++q) {
                const float sq  = (float)((t >> (9 - q)) & 1);
                const float sq1 = (float)((t >> (8 - q)) & 1);
                L += phi[q] * sq * (sq1 - 0.5f);
            }
        } else {              // odd (L0): s_q = t>>(7-q), q=0..7; terms q=0..6
            #pragma unroll
            for (int q = 0; q <= 6; ++q) {
                const float sq  = (float)((t >> (7 - q)) & 1);
                const float sq1 = (float)((t >> (6 - q)) & 1);
                L += phi[q] * sq * (sq1 - 0.5f);
            }
        }
        float s, c;
        __sincosf(L, &s, &c);
        Lt[j * 256 + t] = (f2){c, s};
    }
    __syncthreads();

    // ---- precompute padded transpose indices for all (k, m) ----
    int idx[5][4];
    #pragma unroll
    for (int k = 0; k < 5; ++k) {
        #pragma unroll
        for (int m = 0; m < 4; ++m) {
            const int lo = t & ((1 << (2 * k)) - 1);
            const int d  = lo | (m << (2 * k)) | ((t >> (2 * k)) << (2 * k + 2));
            idx[k][m] = d + (d >> 4);
        }
    }
    const int crossIdx = (((t >> 7) & 1) << 1) | (t & 1);   // (t7<<1)|t0

    #define APPLY(j, q, bit) { \
        const f2* _u = &UT[((j) * NQ + (q)) * 4]; \
        const f2 u0 = _u[0], u1 = _u[1], u2 = _u[2], u3 = _u[3]; \
        _Pragma("unroll") \
        for (int m = 0; m < 4; ++m) if (!(m & (bit))) { \
            const f2 a0 = v[m], a1 = v[m | (bit)]; \
            v[m]         = cmul(u0, a0) + cmul(u1, a1); \
            v[m | (bit)] = cmul(u2, a0) + cmul(u3, a1); \
        } }

    #define TRANS(kF, kT, B) { \
        _Pragma("unroll") \
        for (int m = 0; m < 4; ++m) Tb[B][idx[kF][m]] = v[m]; \
        __syncthreads(); \
        _Pragma("unroll") \
        for (int m = 0; m < 4; ++m) v[m] = Tb[B][idx[kT][m]]; }

    #define CRZ(j) { \
        const f2 l = Lt[(j) * 256 + t]; \
        _Pragma("unroll") \
        for (int m = 0; m < 4; ++m) { \
            const f2 g = Gt[((j) << 4) | (m << 2) | crossIdx]; \
            v[m] = cmul(v[m], cmul(l, g)); \
        } }

    // ---- block 0 collapsed: |0> -> product state in L4 ----
    // L4: d = t | (m<<8); m bit1 = s0, m bit0 = s1; s_q = t>>(9-q) for q>=2.
    f2 v[4];
    {
        f2 f = cmul(UT[2 * 4 + ((t >> 7) & 1) * 2], UT[3 * 4 + ((t >> 6) & 1) * 2]);
        f = cmul(f, cmul(UT[4 * 4 + ((t >> 5) & 1) * 2], UT[5 * 4 + ((t >> 4) & 1) * 2]));
        f = cmul(f, cmul(UT[6 * 4 + ((t >> 3) & 1) * 2], UT[7 * 4 + ((t >> 2) & 1) * 2]));
        f = cmul(f, cmul(UT[8 * 4 + ((t >> 1) & 1) * 2], UT[9 * 4 + (t & 1) * 2]));
        #pragma unroll
        for (int m = 0; m < 4; ++m)
            v[m] = cmul(cmul(UT[0 * 4 + ((m >> 1) & 1) * 2],
                             UT[1 * 4 + (m & 1) * 2]), f);
    }
    CRZ(0)

    // ---- blocks 1..9: odd starts L4 (sweep down), even starts L0 (up) ----
    #pragma unroll 1
    for (int j = 1; j < NB; ++j) {
        if (j & 1) {          // L4 -> L0
            APPLY(j, 1, 1) APPLY(j, 0, 2)
            TRANS(4, 3, 0)
            APPLY(j, 3, 1) APPLY(j, 2, 2)
            TRANS(3, 2, 1)
            APPLY(j, 5, 1) APPLY(j, 4, 2)
            TRANS(2, 1, 0)
            APPLY(j, 7, 1) APPLY(j, 6, 2)
            TRANS(1, 0, 1)
            APPLY(j, 9, 1) APPLY(j, 8, 2)
            CRZ(j)            // odd table = L0 ✓
        } else {              // L0 -> L4
            APPLY(j, 9, 1) APPLY(j, 8, 2)
            TRANS(0, 1, 0)
            APPLY(j, 7, 1) APPLY(j, 6, 2)
            TRANS(1, 2, 1)
            APPLY(j, 5, 1) APPLY(j, 4, 2)
            TRANS(2, 3, 0)
            APPLY(j, 3, 1) APPLY(j, 2, 2)
            TRANS(3, 4, 1)
            APPLY(j, 1, 1) APPLY(j, 0, 2)
            CRZ(j)            // even table = L4 ✓
        }
    }

    // ---- write out: block 9 odd ends in L0: d = m | (t<<2) -> contiguous ----
    float2* o = psi + (size_t)pt * DIM + t * 4;
    *(float4*)&o[0] = make_float4(v[0].x, v[0].y, v[1].x, v[1].y);
    *(float4*)&o[2] = make_float4(v[2].x, v[2].y, v[3].x, v[3].y);
}

// ---------------------------------------------------------------------------
// Kernel B: tiled complex Gram (proven rounds 2/5/6/8-14). 32x32 tile x 16
// K-chunks = 256 blocks. Coalesced float4 staging; A broadcast / Bt <=2-way
// LDS reads; 2x2 register accumulator per thread.
// ---------------------------------------------------------------------------
__global__ __launch_bounds__(256)
void gram_kernel(const float2* __restrict__ psi, float2* __restrict__ Gpart)
{
    __shared__ float2 A [TS][KC + 2];   // pitch 66 float2
    __shared__ float2 Bt[KC][TS + 2];   // pitch 34 float2

    const int tid  = threadIdx.x;
    const int bx   = blockIdx.x;
    const int ks   = bx & 15;
    const int tile = bx >> 4;
    const int ti   = tile >> 2, tj = tile & 3;
    const int kbase = ks * KC;

    #pragma unroll
    for (int it = 0; it < 2; ++it) {
        const int slot = it * 256 + tid;
        const int row  = slot >> 4;          // 0..31
        const int kq   = (slot & 15) << 2;   // 0,4,...,60
        const float4* sa = (const float4*)(psi + (ti * TS + row) * DIM + kbase + kq);
        const float4 a01 = sa[0], a23 = sa[1];
        *(float4*)&A[row][kq]     = a01;
        *(float4*)&A[row][kq + 2] = a23;
        const float4* sb = (const float4*)(psi + (tj * TS + row) * DIM + kbase + kq);
        const float4 b01 = sb[0], b23 = sb[1];
        Bt[kq + 0][row] = make_float2(b01.x, b01.y);
        Bt[kq + 1][row] = make_float2(b01.z, b01.w);
        Bt[kq + 2][row] = make_float2(b23.x, b23.y);
        Bt[kq + 3][row] = make_float2(b23.z, b23.w);
    }
    __syncthreads();

    const int ty = tid >> 4, tx = tid & 15;
    float g00r = 0.f, g00i = 0.f, g01r = 0.f, g01i = 0.f;
    float g10r = 0.f, g10i = 0.f, g11r = 0.f, g11i = 0.f;

    #pragma unroll 4
    for (int k = 0; k < KC; k += 2) {
        const float4 a0 = *(const float4*)&A[2 * ty    ][k];
        const float4 a1 = *(const float4*)&A[2 * ty + 1][k];
        const float4 b0 = *(const float4*)&Bt[k    ][2 * tx];
        const float4 b1 = *(const float4*)&Bt[k + 1][2 * tx];
        g00r += a0.x * b0.x + a0.y * b0.y;  g00i += a0.x * b0.y - a0.y * b0.x;
        g01r += a0.x * b0.z + a0.y * b0.w;  g01i += a0.x * b0.w - a0.y * b0.z;
        g10r += a1.x * b0.x + a1.y * b0.y;  g10i += a1.x * b0.y - a1.y * b0.x;
        g11r += a1.x * b0.z + a1.y * b0.w;  g11i += a1.x * b0.w - a1.y * b0.z;
        g00r += a0.z * b1.x + a0.w * b1.y;  g00i += a0.z * b1.y - a0.w * b1.x;
        g01r += a0.z * b1.z + a0.w * b1.w;  g01i += a0.z * b1.w - a0.w * b1.z;
        g10r += a1.z * b1.x + a1.w * b1.y;  g10i += a1.z * b1.y - a1.w * b1.x;
        g11r += a1.z * b1.z + a1.w * b1.w;  g11i += a1.z * b1.w - a1.w * b1.z;
    }

    float2* gp = Gpart + ks * (NPTS * NPTS);
    const int gr0 = ti * TS + 2 * ty, gc0 = tj * TS + 2 * tx;
    gp[(gr0    ) * NPTS + gc0    ] = make_float2(g00r, g00i);
    gp[(gr0    ) * NPTS + gc0 + 1] = make_float2(g01r, g01i);
    gp[(gr0 + 1) * NPTS + gc0    ] = make_float2(g10r, g10i);
    gp[(gr0 + 1) * NPTS + gc0 + 1] = make_float2(g11r, g11i);
}

// ---------------------------------------------------------------------------
// Kernel C: sum K-partials (coalesced), K = |G|^2, reduce polarity & sum(K^2);
// last-finishing block (atomic counter, proven) writes the scalar.
// ---------------------------------------------------------------------------
__global__ __launch_bounds__(256)
void reduce_final(const float2* __restrict__ Gpart,
                  const float* __restrict__ labels,
                  double* __restrict__ acc,
                  int* __restrict__ cnt,
                  float* __restrict__ out)
{
    const int idx = blockIdx.x * 256 + threadIdx.x;   // 0..16383
    float gr = 0.f, gi = 0.f;
    #pragma unroll
    for (int p = 0; p < KSPLIT; ++p) {
        const float2 g = Gpart[p * (NPTS * NPTS) + idx];
        gr += g.x; gi += g.y;
    }
    const int i  = idx >> 7;
    const int jj = idx & (NPTS - 1);
    const float K = gr * gr + gi * gi;
    double pol = (double)(labels[i] * labels[jj]) * (double)K;
    double k2  = (double)K * (double)K;
    #pragma unroll
    for (int off = 1; off < 64; off <<= 1) {
        pol += __shfl_xor(pol, off, 64);
        k2  += __shfl_xor(k2,  off, 64);
    }
    __shared__ double sp[4], sk[4];
    const int wv = threadIdx.x >> 6;
    if ((threadIdx.x & 63) == 0) { sp[wv] = pol; sk[wv] = k2; }
    __syncthreads();
    if (threadIdx.x == 0) {
        atomicAdd(&acc[0], sp[0] + sp[1] + sp[2] + sp[3]);
        atomicAdd(&acc[1], sk[0] + sk[1] + sk[2] + sk[3]);
        __threadfence();
        const int done = atomicAdd(cnt, 1);
        if (done == NBLK_RED - 1) {
            const double p  = atomicAdd(&acc[0], 0.0);   // atomic read
            const double s2 = atomicAdd(&acc[1], 0.0);
            double sumL2 = 0.0;
            for (int tt = 0; tt < NPTS; ++tt) {
                const double l = (double)labels[tt];
                sumL2 += l * l;
            }
            out[0] = (float)(p / (sumL2 * sqrt(s2)));
        }
    }
}

// ---------------------------------------------------------------------------
extern "C" void kernel_launch(void* const* d_in, const int* in_sizes, int n_in,
                              void* d_out, int out_size, void* d_ws, size_t ws_size,
                              hipStream_t stream)
{
    const float* data   = (const float*)d_in[0];   // [128,100]
    const float* labels = (const float*)d_in[1];   // [128]
    const float* params = (const float*)d_in[2];   // [10,2,10]
    float* out = (float*)d_out;

    float2* psi   = (float2*)d_ws;                                   // 1 MiB
    float2* Gpart = (float2*)((char*)d_ws + (size_t)(1u << 20));     // 2 MiB
    double* acc   = (double*)((char*)d_ws + (size_t)(3u << 20));     // 16 B
    int*    cnt   = (int*)   ((char*)d_ws + (size_t)(3u << 20) + 16);

    states_kernel<<<NPTS, 256, 0, stream>>>(data, params, psi, acc, cnt);
    gram_kernel<<<256, 256, 0, stream>>>(psi, Gpart);
    reduce_final<<<NBLK_RED, 256, 0, stream>>>(Gpart, labels, acc, cnt, out);
}